// Round 6
// baseline (641.070 us; speedup 1.0000x reference)
//
#include <hip/hip_runtime.h>
#include <math.h>

#define N_NODES 50000
#define N_EDGES 800000
#define D_IN    128
#define H_DIM   256
#define L_LAYERS 3
#define SCAN_BLOCKS ((N_NODES + 255) / 256)   // 196

typedef _Float16 f16x8 __attribute__((ext_vector_type(8)));
typedef _Float16 f16x4 __attribute__((ext_vector_type(4)));
typedef float    f32x4 __attribute__((ext_vector_type(4)));

// ---------------- CSR build ----------------

__global__ __launch_bounds__(256) void zero_kernel(int* __restrict__ counts,
                                                   int* __restrict__ cursor, int n) {
    int i = blockIdx.x * 256 + threadIdx.x;
    if (i < n) { counts[i] = 0; cursor[i] = 0; }
}

__global__ __launch_bounds__(256) void hist_kernel(const int* __restrict__ dst,
                                                   int* __restrict__ counts, int e_cnt) {
    int e = blockIdx.x * 256 + threadIdx.x;
    if (e < e_cnt) atomicAdd(&counts[dst[e]], 1);
}

__global__ __launch_bounds__(256) void scanA_kernel(const int* __restrict__ counts,
                                                    int* __restrict__ blocksum,
                                                    float* __restrict__ dinv, int n) {
    __shared__ int s[256];
    int t = threadIdx.x;
    int i = blockIdx.x * 256 + t;
    int v = (i < n) ? counts[i] : 0;
    if (i < n) dinv[i] = rsqrtf((float)(v + 1));
    s[t] = v;
    __syncthreads();
#pragma unroll
    for (int d = 128; d > 0; d >>= 1) {
        if (t < d) s[t] += s[t + d];
        __syncthreads();
    }
    if (t == 0) blocksum[blockIdx.x] = s[0];
}

__global__ __launch_bounds__(256) void scanB_kernel(int* __restrict__ blocksum,
                                                    int* __restrict__ offsets,
                                                    int nblocks, int n, int total) {
    __shared__ int s[256];
    int t = threadIdx.x;
    int v = (t < nblocks) ? blocksum[t] : 0;
    s[t] = v;
    __syncthreads();
#pragma unroll
    for (int d = 1; d < 256; d <<= 1) {
        int x = (t >= d) ? s[t - d] : 0;
        __syncthreads();
        s[t] += x;
        __syncthreads();
    }
    if (t < nblocks) blocksum[t] = s[t] - v;
    if (t == 0) offsets[n] = total;
}

__global__ __launch_bounds__(256) void scanC_kernel(const int* __restrict__ counts,
                                                    const int* __restrict__ blocksum,
                                                    int* __restrict__ offsets, int n) {
    __shared__ int s[256];
    int t = threadIdx.x;
    int i = blockIdx.x * 256 + t;
    int v = (i < n) ? counts[i] : 0;
    s[t] = v;
    __syncthreads();
#pragma unroll
    for (int d = 1; d < 256; d <<= 1) {
        int x = (t >= d) ? s[t - d] : 0;
        __syncthreads();
        s[t] += x;
        __syncthreads();
    }
    if (i < n) offsets[i] = blocksum[blockIdx.x] + s[t] - v;
}

__global__ __launch_bounds__(256) void fill_kernel(const int* __restrict__ src,
                                                   const int* __restrict__ dst,
                                                   const int* __restrict__ offsets,
                                                   int* __restrict__ cursor,
                                                   const float* __restrict__ dinv,
                                                   int* __restrict__ csr_src,
                                                   float* __restrict__ csr_w, int e_cnt) {
    int e = blockIdx.x * 256 + threadIdx.x;
    if (e < e_cnt) {
        int d = dst[e];
        int pos = offsets[d] + atomicAdd(&cursor[d], 1);
        int s = src[e];
        csr_src[pos] = s;
        csr_w[pos]   = dinv[s];
    }
}

// ---------------- aggregation: fp16 gather, fp32 accumulate, unroll-8 ----------------

__global__ __launch_bounds__(256) void aggregate_kernel(const _Float16* __restrict__ h,
                                                        const int* __restrict__ offsets,
                                                        const int* __restrict__ csr_src,
                                                        const float* __restrict__ csr_w,
                                                        const float* __restrict__ dinv,
                                                        _Float16* __restrict__ outp, int n) {
    int wave = threadIdx.x >> 6;
    int lane = threadIdx.x & 63;
    int v = blockIdx.x * 4 + wave;
    if (v >= n) return;
    int c = lane * 4;
    float dv = dinv[v];
    f16x4 self = *(const f16x4*)(h + (size_t)v * H_DIM + c);
    float ax = dv * (float)self[0];
    float ay = dv * (float)self[1];
    float az = dv * (float)self[2];
    float aw = dv * (float)self[3];

    int e  = offsets[v];
    int e1 = offsets[v + 1];

    for (; e + 7 < e1; e += 8) {
        int   s_[8]; float w_[8]; f16x4 r_[8];
#pragma unroll
        for (int j = 0; j < 8; ++j) { s_[j] = csr_src[e + j]; w_[j] = csr_w[e + j]; }
#pragma unroll
        for (int j = 0; j < 8; ++j) r_[j] = *(const f16x4*)(h + (size_t)s_[j] * H_DIM + c);
#pragma unroll
        for (int j = 0; j < 8; ++j) {
            ax += w_[j] * (float)r_[j][0];
            ay += w_[j] * (float)r_[j][1];
            az += w_[j] * (float)r_[j][2];
            aw += w_[j] * (float)r_[j][3];
        }
    }
    if (e + 3 < e1) {
        int   s_[4]; float w_[4]; f16x4 r_[4];
#pragma unroll
        for (int j = 0; j < 4; ++j) { s_[j] = csr_src[e + j]; w_[j] = csr_w[e + j]; }
#pragma unroll
        for (int j = 0; j < 4; ++j) r_[j] = *(const f16x4*)(h + (size_t)s_[j] * H_DIM + c);
#pragma unroll
        for (int j = 0; j < 4; ++j) {
            ax += w_[j] * (float)r_[j][0];
            ay += w_[j] * (float)r_[j][1];
            az += w_[j] * (float)r_[j][2];
            aw += w_[j] * (float)r_[j][3];
        }
        e += 4;
    }
    if (e + 1 < e1) {
        int   s0 = csr_src[e],  s1 = csr_src[e + 1];
        float w0 = csr_w[e],    w1 = csr_w[e + 1];
        f16x4 a = *(const f16x4*)(h + (size_t)s0 * H_DIM + c);
        f16x4 b = *(const f16x4*)(h + (size_t)s1 * H_DIM + c);
        ax += w0 * (float)a[0] + w1 * (float)b[0];
        ay += w0 * (float)a[1] + w1 * (float)b[1];
        az += w0 * (float)a[2] + w1 * (float)b[2];
        aw += w0 * (float)a[3] + w1 * (float)b[3];
        e += 2;
    }
    if (e < e1) {
        int   s0 = csr_src[e];
        float w0 = csr_w[e];
        f16x4 a = *(const f16x4*)(h + (size_t)s0 * H_DIM + c);
        ax += w0 * (float)a[0]; ay += w0 * (float)a[1];
        az += w0 * (float)a[2]; aw += w0 * (float)a[3];
    }
    f16x4 o;
    o[0] = (_Float16)(ax * dv);
    o[1] = (_Float16)(ay * dv);
    o[2] = (_Float16)(az * dv);
    o[3] = (_Float16)(aw * dv);
    *(f16x4*)(outp + (size_t)v * H_DIM + c) = o;
}

// ---------------- weight pre-convert: fp32 [K,256] -> frag-linear f16 hi/lo ----------------
// dst = base + (k>>5)*8192 + (n>>4)*512 + ((k&31)>>3)*128 + (n&15)*8 + (k&7)

#define WCONV_TOTAL 294912

__global__ __launch_bounds__(256) void wconv_kernel(const float* __restrict__ W_enc,
                                                    const float* __restrict__ W_g,
                                                    const float* __restrict__ W_out,
                                                    _Float16* __restrict__ whi,
                                                    _Float16* __restrict__ wlo) {
    int gid = blockIdx.x * 256 + threadIdx.x;
    if (gid >= WCONV_TOTAL) return;
    const float* src; int base, e;
    if (gid < 32768)       { src = W_enc; base = 0;      e = gid; }
    else if (gid < 229376) { src = W_g;   base = 32768;  e = gid - 32768; }
    else                   { src = W_out; base = 229376; e = gid - 229376; }
    int k = e >> 8;
    int n = e & 255;
    float x = src[e];
    _Float16 hb = (_Float16)x;
    _Float16 lb = (_Float16)(x - (float)hb);
    int dst = base + (k >> 5) * 8192 + (n >> 4) * 512 + ((k & 31) >> 3) * 128
            + (n & 15) * 8 + (k & 7);
    whi[dst] = hb;
    wlo[dst] = lb;
}

// ---------------- persistent col-quarter MFMA GEMM, W staged ONCE, barrier-free K-loop ----
// grid = 512 blocks; quarter q = bid&3 (64 cols), row-tiles of 256 rows strided by 128.
// block: 4 waves, wave w -> rows [64w,64w+64) of the tile, all waves share the 64 cols.
// W quarter (full K, hi+lo) staged once into LDS; M/K loops have NO barriers.

template <int KC, int AMODE, int OUT16>
__global__ __launch_bounds__(256, 2) void mfma_gemm(const float* __restrict__ Af,
                                                    const _Float16* __restrict__ A16,
                                                    const _Float16* __restrict__ WhG,
                                                    const _Float16* __restrict__ WlG,
                                                    const float* __restrict__ bias,
                                                    float* __restrict__ Cf,
                                                    _Float16* __restrict__ Ch,
                                                    int n, int relu) {
    constexpr int K = KC * 32;
    __shared__ _Float16 Wh[KC * 2048];   // [kc][nt'(4)][lane(64)][j(8)]
    __shared__ _Float16 Wl[KC * 2048];

    int t = threadIdx.x;
    int w = t >> 6;
    int lane = t & 63;
    int q = blockIdx.x & 3;
    int colbase = q * 64;
    int mrow = lane & 15;
    int koct = (lane >> 4) * 8;

    // ---- stage W quarter once (4 KB per kc per array, lane-linear) ----
#pragma unroll
    for (int kc = 0; kc < KC; ++kc) {
        __builtin_amdgcn_global_load_lds(
            (const __attribute__((address_space(1))) unsigned int*)(WhG + kc * 8192 + q * 2048 + t * 8),
            (__attribute__((address_space(3))) unsigned int*)(&Wh[kc * 2048 + t * 8]), 16, 0, 0);
        __builtin_amdgcn_global_load_lds(
            (const __attribute__((address_space(1))) unsigned int*)(WlG + kc * 8192 + q * 2048 + t * 8),
            (__attribute__((address_space(3))) unsigned int*)(&Wl[kc * 2048 + t * 8]), 16, 0, 0);
    }
    __syncthreads();

    int colq = lane & 15;
    int rowq = (lane >> 4) * 4;
    float bcol[4];
#pragma unroll
    for (int c = 0; c < 4; ++c) bcol[c] = bias[colbase + c * 16 + colq];

    for (int rt = blockIdx.x >> 2; rt * 256 < n; rt += 128) {
        int rbase = rt * 256 + w * 64;
        int rows[4];
#pragma unroll
        for (int mt = 0; mt < 4; ++mt) {
            int r = rbase + mt * 16 + mrow;
            rows[mt] = (r < n) ? r : (n - 1);   // clamp: dup rows, never stored
        }

        f32x4 acc[4][4];
#pragma unroll
        for (int mt = 0; mt < 4; ++mt)
#pragma unroll
            for (int c = 0; c < 4; ++c)
                acc[mt][c] = (f32x4)(0.0f);

        // A prefetch registers (one kc ahead)
        f16x8 a16c[4], a16n[4];
        float4 af0c[4], af1c[4], af0n[4], af1n[4];
        if (AMODE == 1) {
#pragma unroll
            for (int mt = 0; mt < 4; ++mt)
                a16c[mt] = *(const f16x8*)(A16 + (size_t)rows[mt] * K + koct);
        } else {
#pragma unroll
            for (int mt = 0; mt < 4; ++mt) {
                const float* p = Af + (size_t)rows[mt] * K + koct;
                af0c[mt] = *(const float4*)p;
                af1c[mt] = *(const float4*)(p + 4);
            }
        }

#pragma unroll
        for (int kc = 0; kc < KC; ++kc) {
            if (kc + 1 < KC) {
                if (AMODE == 1) {
#pragma unroll
                    for (int mt = 0; mt < 4; ++mt)
                        a16n[mt] = *(const f16x8*)(A16 + (size_t)rows[mt] * K + (kc + 1) * 32 + koct);
                } else {
#pragma unroll
                    for (int mt = 0; mt < 4; ++mt) {
                        const float* p = Af + (size_t)rows[mt] * K + (kc + 1) * 32 + koct;
                        af0n[mt] = *(const float4*)p;
                        af1n[mt] = *(const float4*)(p + 4);
                    }
                }
            }

            f16x8 ah[4], al[4];
            if (AMODE == 1) {
#pragma unroll
                for (int mt = 0; mt < 4; ++mt) ah[mt] = a16c[mt];
            } else {
#pragma unroll
                for (int mt = 0; mt < 4; ++mt) {
                    float xs[8] = {af0c[mt].x, af0c[mt].y, af0c[mt].z, af0c[mt].w,
                                   af1c[mt].x, af1c[mt].y, af1c[mt].z, af1c[mt].w};
                    f16x8 H, L;
#pragma unroll
                    for (int j = 0; j < 8; ++j) {
                        _Float16 hb = (_Float16)xs[j];
                        H[j] = hb;
                        L[j] = (_Float16)(xs[j] - (float)hb);
                    }
                    ah[mt] = H;
                    al[mt] = L;
                }
            }

#pragma unroll
            for (int c = 0; c < 4; ++c) {
                f16x8 bh = *(const f16x8*)&Wh[kc * 2048 + c * 512 + lane * 8];
                f16x8 bl = *(const f16x8*)&Wl[kc * 2048 + c * 512 + lane * 8];
#pragma unroll
                for (int mt = 0; mt < 4; ++mt) {
                    acc[mt][c] = __builtin_amdgcn_mfma_f32_16x16x32_f16(ah[mt], bh, acc[mt][c], 0, 0, 0);
                    acc[mt][c] = __builtin_amdgcn_mfma_f32_16x16x32_f16(ah[mt], bl, acc[mt][c], 0, 0, 0);
                    if (AMODE == 0)
                        acc[mt][c] = __builtin_amdgcn_mfma_f32_16x16x32_f16(al[mt], bh, acc[mt][c], 0, 0, 0);
                }
            }

            if (AMODE == 1) {
#pragma unroll
                for (int mt = 0; mt < 4; ++mt) a16c[mt] = a16n[mt];
            } else {
#pragma unroll
                for (int mt = 0; mt < 4; ++mt) {
                    af0c[mt] = af0n[mt];
                    af1c[mt] = af1n[mt];
                }
            }
        }

        // ---- epilogue: C/D layout col=lane&15, row=(lane>>4)*4+reg ----
#pragma unroll
        for (int c = 0; c < 4; ++c) {
            int col = colbase + c * 16 + colq;
#pragma unroll
            for (int mt = 0; mt < 4; ++mt) {
                int rb = rbase + mt * 16 + rowq;
#pragma unroll
                for (int r = 0; r < 4; ++r) {
                    int row = rb + r;
                    if (row < n) {
                        float v = acc[mt][c][r] + bcol[c];
                        if (relu) v = fmaxf(v, 0.f);
                        if (OUT16) Ch[(size_t)row * H_DIM + col] = (_Float16)v;
                        else       Cf[(size_t)row * H_DIM + col] = v;
                    }
                }
            }
        }
    }
}

// ---------------- launch ----------------

extern "C" void kernel_launch(void* const* d_in, const int* in_sizes, int n_in,
                              void* d_out, int out_size, void* d_ws, size_t ws_size,
                              hipStream_t stream) {
    const float* x     = (const float*)d_in[0];
    const int*   ei    = (const int*)d_in[1];
    const float* W_enc = (const float*)d_in[3];
    const float* b_enc = (const float*)d_in[4];
    const float* W_g   = (const float*)d_in[5];
    const float* b_g   = (const float*)d_in[6];
    const float* W_out = (const float*)d_in[7];
    const float* b_out = (const float*)d_in[8];
    float* out = (float*)d_out;

    char* ws = (char*)d_ws;
    size_t off = 0;
    auto alloc = [&](size_t bytes) -> void* {
        void* p = ws + off;
        off = (off + bytes + 255) & ~(size_t)255;
        return p;
    };
    int*       counts   = (int*)alloc((size_t)N_NODES * 4);
    int*       offsets  = (int*)alloc((size_t)(N_NODES + 1) * 4);
    int*       cursor   = (int*)alloc((size_t)N_NODES * 4);
    float*     dinv     = (float*)alloc((size_t)N_NODES * 4);
    int*       blocksum = (int*)alloc((size_t)SCAN_BLOCKS * 4);
    int*       csr_src  = (int*)alloc((size_t)N_EDGES * 4);
    float*     csr_w    = (float*)alloc((size_t)N_EDGES * 4);
    _Float16*  h16      = (_Float16*)alloc((size_t)N_NODES * H_DIM * 2);
    _Float16*  agg16    = (_Float16*)alloc((size_t)N_NODES * H_DIM * 2);
    _Float16*  whi      = (_Float16*)alloc((size_t)WCONV_TOTAL * 2);
    _Float16*  wlo      = (_Float16*)alloc((size_t)WCONV_TOTAL * 2);

    const int* src = ei;
    const int* dst = ei + N_EDGES;

    zero_kernel<<<(N_NODES + 255) / 256, 256, 0, stream>>>(counts, cursor, N_NODES);
    hist_kernel<<<(N_EDGES + 255) / 256, 256, 0, stream>>>(dst, counts, N_EDGES);
    scanA_kernel<<<SCAN_BLOCKS, 256, 0, stream>>>(counts, blocksum, dinv, N_NODES);
    scanB_kernel<<<1, 256, 0, stream>>>(blocksum, offsets, SCAN_BLOCKS, N_NODES, N_EDGES);
    scanC_kernel<<<SCAN_BLOCKS, 256, 0, stream>>>(counts, blocksum, offsets, N_NODES);
    fill_kernel<<<(N_EDGES + 255) / 256, 256, 0, stream>>>(src, dst, offsets, cursor, dinv,
                                                           csr_src, csr_w, N_EDGES);
    wconv_kernel<<<(WCONV_TOTAL + 255) / 256, 256, 0, stream>>>(W_enc, W_g, W_out, whi, wlo);

    // encoder: h1 = relu(x @ W_enc + b_enc)  — KC=4 (K=128), fp32 A inline-split
    mfma_gemm<4, 0, 1><<<512, 256, 0, stream>>>(x, (const _Float16*)nullptr,
                                                whi, wlo, b_enc,
                                                (float*)nullptr, h16, N_NODES, 1);
    // 3 GCN layers
    for (int l = 0; l < L_LAYERS; ++l) {
        aggregate_kernel<<<N_NODES / 4, 256, 0, stream>>>(h16, offsets, csr_src, csr_w, dinv,
                                                          agg16, N_NODES);
        mfma_gemm<8, 1, 1><<<512, 256, 0, stream>>>((const float*)nullptr, agg16,
                                                    whi + 32768 + (size_t)l * 65536,
                                                    wlo + 32768 + (size_t)l * 65536,
                                                    b_g + (size_t)l * H_DIM,
                                                    (float*)nullptr, h16, N_NODES, 1);
    }
    // output head (no relu), f16 A, fp32 out
    mfma_gemm<8, 1, 0><<<512, 256, 0, stream>>>((const float*)nullptr, h16,
                                                whi + 229376, wlo + 229376, b_out,
                                                out, (_Float16*)nullptr, N_NODES, 0);
}

// Round 7
// 530.234 us; speedup vs baseline: 1.2090x; 1.2090x over previous
//
#include <hip/hip_runtime.h>
#include <math.h>

#define N_NODES 50000
#define N_EDGES 800000
#define D_IN    128
#define H_DIM   256
#define L_LAYERS 3
#define SCAN_BLOCKS ((N_NODES + 255) / 256)   // 196

typedef _Float16 f16x8 __attribute__((ext_vector_type(8)));
typedef _Float16 f16x4 __attribute__((ext_vector_type(4)));
typedef float    f32x4 __attribute__((ext_vector_type(4)));

// ---------------- CSR build ----------------

__global__ __launch_bounds__(256) void zero_kernel(int* __restrict__ counts,
                                                   int* __restrict__ cursor, int n) {
    int i = blockIdx.x * 256 + threadIdx.x;
    if (i < n) { counts[i] = 0; cursor[i] = 0; }
}

__global__ __launch_bounds__(256) void hist_kernel(const int* __restrict__ dst,
                                                   int* __restrict__ counts, int e_cnt) {
    int e = blockIdx.x * 256 + threadIdx.x;
    if (e < e_cnt) atomicAdd(&counts[dst[e]], 1);
}

__global__ __launch_bounds__(256) void scanA_kernel(const int* __restrict__ counts,
                                                    int* __restrict__ blocksum,
                                                    float* __restrict__ dinv, int n) {
    __shared__ int s[256];
    int t = threadIdx.x;
    int i = blockIdx.x * 256 + t;
    int v = (i < n) ? counts[i] : 0;
    if (i < n) dinv[i] = rsqrtf((float)(v + 1));
    s[t] = v;
    __syncthreads();
#pragma unroll
    for (int d = 128; d > 0; d >>= 1) {
        if (t < d) s[t] += s[t + d];
        __syncthreads();
    }
    if (t == 0) blocksum[blockIdx.x] = s[0];
}

__global__ __launch_bounds__(256) void scanB_kernel(int* __restrict__ blocksum,
                                                    int* __restrict__ offsets,
                                                    int nblocks, int n, int total) {
    __shared__ int s[256];
    int t = threadIdx.x;
    int v = (t < nblocks) ? blocksum[t] : 0;
    s[t] = v;
    __syncthreads();
#pragma unroll
    for (int d = 1; d < 256; d <<= 1) {
        int x = (t >= d) ? s[t - d] : 0;
        __syncthreads();
        s[t] += x;
        __syncthreads();
    }
    if (t < nblocks) blocksum[t] = s[t] - v;
    if (t == 0) offsets[n] = total;
}

__global__ __launch_bounds__(256) void scanC_kernel(const int* __restrict__ counts,
                                                    const int* __restrict__ blocksum,
                                                    int* __restrict__ offsets, int n) {
    __shared__ int s[256];
    int t = threadIdx.x;
    int i = blockIdx.x * 256 + t;
    int v = (i < n) ? counts[i] : 0;
    s[t] = v;
    __syncthreads();
#pragma unroll
    for (int d = 1; d < 256; d <<= 1) {
        int x = (t >= d) ? s[t - d] : 0;
        __syncthreads();
        s[t] += x;
        __syncthreads();
    }
    if (i < n) offsets[i] = blocksum[blockIdx.x] + s[t] - v;
}

__global__ __launch_bounds__(256) void fill_kernel(const int* __restrict__ src,
                                                   const int* __restrict__ dst,
                                                   const int* __restrict__ offsets,
                                                   int* __restrict__ cursor,
                                                   const float* __restrict__ dinv,
                                                   int* __restrict__ csr_src,
                                                   float* __restrict__ csr_w, int e_cnt) {
    int e = blockIdx.x * 256 + threadIdx.x;
    if (e < e_cnt) {
        int d = dst[e];
        int pos = offsets[d] + atomicAdd(&cursor[d], 1);
        int s = src[e];
        csr_src[pos] = s;
        csr_w[pos]   = dinv[s];
    }
}

// ---------------- aggregation: fp16 gather, fp32 accumulate, unroll-16 ----------------

__global__ __launch_bounds__(256) void aggregate_kernel(const _Float16* __restrict__ h,
                                                        const int* __restrict__ offsets,
                                                        const int* __restrict__ csr_src,
                                                        const float* __restrict__ csr_w,
                                                        const float* __restrict__ dinv,
                                                        _Float16* __restrict__ outp, int n) {
    int wave = threadIdx.x >> 6;
    int lane = threadIdx.x & 63;
    int v = blockIdx.x * 4 + wave;
    if (v >= n) return;
    int c = lane * 4;
    float dv = dinv[v];
    f16x4 self = *(const f16x4*)(h + (size_t)v * H_DIM + c);
    float ax = dv * (float)self[0];
    float ay = dv * (float)self[1];
    float az = dv * (float)self[2];
    float aw = dv * (float)self[3];

    int e  = offsets[v];
    int e1 = offsets[v + 1];

    for (; e + 15 < e1; e += 16) {
        int   s_[16]; float w_[16]; f16x4 r_[16];
#pragma unroll
        for (int j = 0; j < 16; ++j) { s_[j] = csr_src[e + j]; w_[j] = csr_w[e + j]; }
#pragma unroll
        for (int j = 0; j < 16; ++j) r_[j] = *(const f16x4*)(h + (size_t)s_[j] * H_DIM + c);
#pragma unroll
        for (int j = 0; j < 16; ++j) {
            ax += w_[j] * (float)r_[j][0];
            ay += w_[j] * (float)r_[j][1];
            az += w_[j] * (float)r_[j][2];
            aw += w_[j] * (float)r_[j][3];
        }
    }
    if (e + 7 < e1) {
        int   s_[8]; float w_[8]; f16x4 r_[8];
#pragma unroll
        for (int j = 0; j < 8; ++j) { s_[j] = csr_src[e + j]; w_[j] = csr_w[e + j]; }
#pragma unroll
        for (int j = 0; j < 8; ++j) r_[j] = *(const f16x4*)(h + (size_t)s_[j] * H_DIM + c);
#pragma unroll
        for (int j = 0; j < 8; ++j) {
            ax += w_[j] * (float)r_[j][0];
            ay += w_[j] * (float)r_[j][1];
            az += w_[j] * (float)r_[j][2];
            aw += w_[j] * (float)r_[j][3];
        }
        e += 8;
    }
    if (e + 3 < e1) {
        int   s_[4]; float w_[4]; f16x4 r_[4];
#pragma unroll
        for (int j = 0; j < 4; ++j) { s_[j] = csr_src[e + j]; w_[j] = csr_w[e + j]; }
#pragma unroll
        for (int j = 0; j < 4; ++j) r_[j] = *(const f16x4*)(h + (size_t)s_[j] * H_DIM + c);
#pragma unroll
        for (int j = 0; j < 4; ++j) {
            ax += w_[j] * (float)r_[j][0];
            ay += w_[j] * (float)r_[j][1];
            az += w_[j] * (float)r_[j][2];
            aw += w_[j] * (float)r_[j][3];
        }
        e += 4;
    }
    if (e + 1 < e1) {
        int   s0 = csr_src[e],  s1 = csr_src[e + 1];
        float w0 = csr_w[e],    w1 = csr_w[e + 1];
        f16x4 a = *(const f16x4*)(h + (size_t)s0 * H_DIM + c);
        f16x4 b = *(const f16x4*)(h + (size_t)s1 * H_DIM + c);
        ax += w0 * (float)a[0] + w1 * (float)b[0];
        ay += w0 * (float)a[1] + w1 * (float)b[1];
        az += w0 * (float)a[2] + w1 * (float)b[2];
        aw += w0 * (float)a[3] + w1 * (float)b[3];
        e += 2;
    }
    if (e < e1) {
        int   s0 = csr_src[e];
        float w0 = csr_w[e];
        f16x4 a = *(const f16x4*)(h + (size_t)s0 * H_DIM + c);
        ax += w0 * (float)a[0]; ay += w0 * (float)a[1];
        az += w0 * (float)a[2]; aw += w0 * (float)a[3];
    }
    f16x4 o;
    o[0] = (_Float16)(ax * dv);
    o[1] = (_Float16)(ay * dv);
    o[2] = (_Float16)(az * dv);
    o[3] = (_Float16)(aw * dv);
    *(f16x4*)(outp + (size_t)v * H_DIM + c) = o;
}

// ---------------- weight pre-convert: fp32 [K,256] -> frag-linear f16 hi/lo ----------------
// dst = base + (k>>5)*8192 + (n>>4)*512 + ((k&31)>>3)*128 + (n&15)*8 + (k&7)

#define WCONV_TOTAL 294912

__global__ __launch_bounds__(256) void wconv_kernel(const float* __restrict__ W_enc,
                                                    const float* __restrict__ W_g,
                                                    const float* __restrict__ W_out,
                                                    _Float16* __restrict__ whi,
                                                    _Float16* __restrict__ wlo) {
    int gid = blockIdx.x * 256 + threadIdx.x;
    if (gid >= WCONV_TOTAL) return;
    const float* src; int base, e;
    if (gid < 32768)       { src = W_enc; base = 0;      e = gid; }
    else if (gid < 229376) { src = W_g;   base = 32768;  e = gid - 32768; }
    else                   { src = W_out; base = 229376; e = gid - 229376; }
    int k = e >> 8;
    int n = e & 255;
    float x = src[e];
    _Float16 hb = (_Float16)x;
    _Float16 lb = (_Float16)(x - (float)hb);
    int dst = base + (k >> 5) * 8192 + (n >> 4) * 512 + ((k & 31) >> 3) * 128
            + (n & 15) * 8 + (k & 7);
    whi[dst] = hb;
    wlo[dst] = lb;
}

// ---------------- col-quarter MFMA GEMM, XCD-aligned, phased W staging ----------------
// grid = 1024: q = bid>>8 (col quarter, 64 cols), rt = bid&255 (256-row tile; dead
// blocks exit). Same-rt quarters differ by 256 ≡ 0 mod 8 -> SAME XCD -> A row-tile
// is HBM-fetched once, L2-served 3x. W quarter staged in K-phases of 4 kc (32 KB LDS,
// 4 blocks/CU); one restage barrier mid-loop for K=256. A: depth-2 register prefetch.

template <int KC, int AMODE, int OUT16>
__global__ __launch_bounds__(256, 4) void mfma_gemm(const float* __restrict__ Af,
                                                    const _Float16* __restrict__ A16,
                                                    const _Float16* __restrict__ WhG,
                                                    const _Float16* __restrict__ WlG,
                                                    const float* __restrict__ bias,
                                                    float* __restrict__ Cf,
                                                    _Float16* __restrict__ Ch,
                                                    int n, int relu) {
    constexpr int K   = KC * 32;
    constexpr int PKC = (KC >= 8) ? 4 : KC;   // kc per staging phase
    constexpr int NPH = KC / PKC;
    __shared__ _Float16 Wlds[PKC * 2 * 2048]; // [pk][hi/lo][c(4)][lane(64)][j(8)] = 32 KB

    int t = threadIdx.x;
    int w = t >> 6;
    int lane = t & 63;
    int q  = blockIdx.x >> 8;
    int rt = blockIdx.x & 255;
    if (rt * 256 >= n) return;
    int colbase = q * 64;
    int mrow = lane & 15;
    int koct = (lane >> 4) * 8;
    int rbase = rt * 256 + w * 64;

    int rows[4];
#pragma unroll
    for (int mt = 0; mt < 4; ++mt) {
        int r = rbase + mt * 16 + mrow;
        rows[mt] = (r < n) ? r : (n - 1);     // clamp: dup rows, never stored
    }

    f32x4 acc[4][4];
#pragma unroll
    for (int mt = 0; mt < 4; ++mt)
#pragma unroll
        for (int c = 0; c < 4; ++c)
            acc[mt][c] = (f32x4)(0.0f);

    // ---- A register pipeline ----
    f16x8 a16p[2][4];                 // AMODE 1: depth-2
    float4 af0[4], af1[4];            // AMODE 0: depth-1
    if (AMODE == 1) {
#pragma unroll
        for (int mt = 0; mt < 4; ++mt) {
            a16p[0][mt] = *(const f16x8*)(A16 + (size_t)rows[mt] * K + koct);
            a16p[1][mt] = *(const f16x8*)(A16 + (size_t)rows[mt] * K + 32 + koct);
        }
    } else {
#pragma unroll
        for (int mt = 0; mt < 4; ++mt) {
            const float* p = Af + (size_t)rows[mt] * K + koct;
            af0[mt] = *(const float4*)p;
            af1[mt] = *(const float4*)(p + 4);
        }
    }

#pragma unroll
    for (int ph = 0; ph < NPH; ++ph) {
        if (ph) __syncthreads();              // all waves done reading previous phase
        // ---- stage phase: PKC kc-chunks, hi+lo, lane-linear 16B copies ----
#pragma unroll
        for (int pk = 0; pk < PKC; ++pk) {
            int kc = ph * PKC + pk;
            __builtin_amdgcn_global_load_lds(
                (const __attribute__((address_space(1))) unsigned int*)(WhG + (size_t)kc * 8192 + q * 2048 + t * 8),
                (__attribute__((address_space(3))) unsigned int*)(&Wlds[(pk * 2 + 0) * 2048 + t * 8]), 16, 0, 0);
            __builtin_amdgcn_global_load_lds(
                (const __attribute__((address_space(1))) unsigned int*)(WlG + (size_t)kc * 8192 + q * 2048 + t * 8),
                (__attribute__((address_space(3))) unsigned int*)(&Wlds[(pk * 2 + 1) * 2048 + t * 8]), 16, 0, 0);
        }
        __syncthreads();

#pragma unroll
        for (int pk = 0; pk < PKC; ++pk) {
            int kc = ph * PKC + pk;
            f16x8 ah[4], al[4];
            if (AMODE == 0) {
#pragma unroll
                for (int mt = 0; mt < 4; ++mt) {
                    float4 c0 = af0[mt], c1 = af1[mt];
                    if (kc + 1 < KC) {
                        const float* p = Af + (size_t)rows[mt] * K + (kc + 1) * 32 + koct;
                        af0[mt] = *(const float4*)p;
                        af1[mt] = *(const float4*)(p + 4);
                    }
                    float xs[8] = {c0.x, c0.y, c0.z, c0.w, c1.x, c1.y, c1.z, c1.w};
                    f16x8 H, L;
#pragma unroll
                    for (int j = 0; j < 8; ++j) {
                        _Float16 hb = (_Float16)xs[j];
                        H[j] = hb;
                        L[j] = (_Float16)(xs[j] - (float)hb);
                    }
                    ah[mt] = H;
                    al[mt] = L;
                }
            }

#pragma unroll
            for (int c = 0; c < 4; ++c) {
                f16x8 bh = *(const f16x8*)&Wlds[(pk * 2 + 0) * 2048 + c * 512 + lane * 8];
                f16x8 bl = *(const f16x8*)&Wlds[(pk * 2 + 1) * 2048 + c * 512 + lane * 8];
#pragma unroll
                for (int mt = 0; mt < 4; ++mt) {
                    if (AMODE == 1) {
                        f16x8 a = a16p[kc & 1][mt];
                        acc[mt][c] = __builtin_amdgcn_mfma_f32_16x16x32_f16(a, bh, acc[mt][c], 0, 0, 0);
                        acc[mt][c] = __builtin_amdgcn_mfma_f32_16x16x32_f16(a, bl, acc[mt][c], 0, 0, 0);
                    } else {
                        acc[mt][c] = __builtin_amdgcn_mfma_f32_16x16x32_f16(ah[mt], bh, acc[mt][c], 0, 0, 0);
                        acc[mt][c] = __builtin_amdgcn_mfma_f32_16x16x32_f16(ah[mt], bl, acc[mt][c], 0, 0, 0);
                        acc[mt][c] = __builtin_amdgcn_mfma_f32_16x16x32_f16(al[mt], bh, acc[mt][c], 0, 0, 0);
                    }
                }
            }

            if (AMODE == 1 && kc + 2 < KC) {
#pragma unroll
                for (int mt = 0; mt < 4; ++mt)
                    a16p[kc & 1][mt] = *(const f16x8*)(A16 + (size_t)rows[mt] * K + (kc + 2) * 32 + koct);
            }
        }
    }

    // ---- epilogue: C/D layout col=lane&15, row=(lane>>4)*4+reg ----
    int colq = lane & 15;
    int rowq = (lane >> 4) * 4;
#pragma unroll
    for (int c = 0; c < 4; ++c) {
        int col = colbase + c * 16 + colq;
        float b = bias[col];
#pragma unroll
        for (int mt = 0; mt < 4; ++mt) {
            int rb = rbase + mt * 16 + rowq;
#pragma unroll
            for (int r = 0; r < 4; ++r) {
                int row = rb + r;
                if (row < n) {
                    float v = acc[mt][c][r] + b;
                    if (relu) v = fmaxf(v, 0.f);
                    if (OUT16) Ch[(size_t)row * H_DIM + col] = (_Float16)v;
                    else       Cf[(size_t)row * H_DIM + col] = v;
                }
            }
        }
    }
}

// ---------------- launch ----------------

extern "C" void kernel_launch(void* const* d_in, const int* in_sizes, int n_in,
                              void* d_out, int out_size, void* d_ws, size_t ws_size,
                              hipStream_t stream) {
    const float* x     = (const float*)d_in[0];
    const int*   ei    = (const int*)d_in[1];
    const float* W_enc = (const float*)d_in[3];
    const float* b_enc = (const float*)d_in[4];
    const float* W_g   = (const float*)d_in[5];
    const float* b_g   = (const float*)d_in[6];
    const float* W_out = (const float*)d_in[7];
    const float* b_out = (const float*)d_in[8];
    float* out = (float*)d_out;

    char* ws = (char*)d_ws;
    size_t off = 0;
    auto alloc = [&](size_t bytes) -> void* {
        void* p = ws + off;
        off = (off + bytes + 255) & ~(size_t)255;
        return p;
    };
    int*       counts   = (int*)alloc((size_t)N_NODES * 4);
    int*       offsets  = (int*)alloc((size_t)(N_NODES + 1) * 4);
    int*       cursor   = (int*)alloc((size_t)N_NODES * 4);
    float*     dinv     = (float*)alloc((size_t)N_NODES * 4);
    int*       blocksum = (int*)alloc((size_t)SCAN_BLOCKS * 4);
    int*       csr_src  = (int*)alloc((size_t)N_EDGES * 4);
    float*     csr_w    = (float*)alloc((size_t)N_EDGES * 4);
    _Float16*  h16      = (_Float16*)alloc((size_t)N_NODES * H_DIM * 2);
    _Float16*  agg16    = (_Float16*)alloc((size_t)N_NODES * H_DIM * 2);
    _Float16*  whi      = (_Float16*)alloc((size_t)WCONV_TOTAL * 2);
    _Float16*  wlo      = (_Float16*)alloc((size_t)WCONV_TOTAL * 2);

    const int* src = ei;
    const int* dst = ei + N_EDGES;

    zero_kernel<<<(N_NODES + 255) / 256, 256, 0, stream>>>(counts, cursor, N_NODES);
    hist_kernel<<<(N_EDGES + 255) / 256, 256, 0, stream>>>(dst, counts, N_EDGES);
    scanA_kernel<<<SCAN_BLOCKS, 256, 0, stream>>>(counts, blocksum, dinv, N_NODES);
    scanB_kernel<<<1, 256, 0, stream>>>(blocksum, offsets, SCAN_BLOCKS, N_NODES, N_EDGES);
    scanC_kernel<<<SCAN_BLOCKS, 256, 0, stream>>>(counts, blocksum, offsets, N_NODES);
    fill_kernel<<<(N_EDGES + 255) / 256, 256, 0, stream>>>(src, dst, offsets, cursor, dinv,
                                                           csr_src, csr_w, N_EDGES);
    wconv_kernel<<<(WCONV_TOTAL + 255) / 256, 256, 0, stream>>>(W_enc, W_g, W_out, whi, wlo);

    // encoder: h1 = relu(x @ W_enc + b_enc)  — KC=4 (K=128), fp32 A inline-split
    mfma_gemm<4, 0, 1><<<1024, 256, 0, stream>>>(x, (const _Float16*)nullptr,
                                                 whi, wlo, b_enc,
                                                 (float*)nullptr, h16, N_NODES, 1);
    // 3 GCN layers
    for (int l = 0; l < L_LAYERS; ++l) {
        aggregate_kernel<<<N_NODES / 4, 256, 0, stream>>>(h16, offsets, csr_src, csr_w, dinv,
                                                          agg16, N_NODES);
        mfma_gemm<8, 1, 1><<<1024, 256, 0, stream>>>((const float*)nullptr, agg16,
                                                     whi + 32768 + (size_t)l * 65536,
                                                     wlo + 32768 + (size_t)l * 65536,
                                                     b_g + (size_t)l * H_DIM,
                                                     (float*)nullptr, h16, N_NODES, 1);
    }
    // output head (no relu), f16 A, fp32 out
    mfma_gemm<8, 1, 0><<<1024, 256, 0, stream>>>((const float*)nullptr, h16,
                                                 whi + 229376, wlo + 229376, b_out,
                                                 out, (_Float16*)nullptr, N_NODES, 0);
}